// Round 6
// baseline (50.699 us; speedup 1.0000x reference)
//
#include <hip/hip_runtime.h>
#include <math.h>

#define SRATE   24000.0
#define NB      8
#define NT      48000
#define NH      60
#define NC      100
#define NFMT    5
#define CTS     64                        // timesteps per chunk
#define NCH     (NT / CTS)                // 750 chunks per batch
#define TWO_PI  6.283185307179586476925286766559
#define TPB     1024
#define TILE    (TPB * 4)

typedef float v2f __attribute__((ext_vector_type(2)));

// ---- kernel 1: fused f0 scan -> prep[t] = (f0[t], rev[t]) + final phase ----
// One block per batch, 1024 threads, 12 tiles of 4096 timesteps with
// software-prefetched loads. rev in double, reduced mod 1, stored f32.
__global__ __launch_bounds__(TPB) void k_prep(const float* __restrict__ f0,
                                              const float* __restrict__ initp,
                                              float2* __restrict__ prep,
                                              float* __restrict__ outf) {
    int b = blockIdx.x, tid = threadIdx.x;
    int lane = tid & 63, wv = tid >> 6;
    __shared__ double wsum[TPB / 64];
    const float* fb = f0 + (size_t)b * NT;
    double initrev = (double)initp[b] * (1.0 / TWO_PI);
    double carry = 0.0;
    int t0 = tid * 4;
    float4 fv = (t0 < NT) ? *(const float4*)(fb + t0) : make_float4(0, 0, 0, 0);
    for (int tile = 0; tile < NT; tile += TILE) {
        int nt0 = tile + TILE + tid * 4;
        float4 nxt = (nt0 < NT) ? *(const float4*)(fb + nt0) : make_float4(0, 0, 0, 0);
        double p0 = fv.x, p1 = p0 + fv.y, p2 = p1 + fv.z, p3 = p2 + fv.w;
        double inc = p3;
        #pragma unroll
        for (int off = 1; off < 64; off <<= 1) {
            double n = __shfl_up(inc, off, 64);
            if (lane >= off) inc += n;
        }
        if (lane == 63) wsum[wv] = inc;
        __syncthreads();
        double woff = carry, tot = 0.0;
        #pragma unroll
        for (int w = 0; w < TPB / 64; ++w) {
            double v = wsum[w];
            tot += v;
            if (w < wv) woff += v;
        }
        __syncthreads();
        int ct0 = tile + tid * 4;
        if (ct0 < NT) {
            double base = woff + inc - p3;     // exclusive prefix for this thread
            float4 lo, hi;
            double r;
            r = (base + p0) * (1.0 / SRATE) + initrev; lo.x = fv.x; lo.y = (float)(r - floor(r));
            r = (base + p1) * (1.0 / SRATE) + initrev; lo.z = fv.y; lo.w = (float)(r - floor(r));
            r = (base + p2) * (1.0 / SRATE) + initrev; hi.x = fv.z; hi.y = (float)(r - floor(r));
            r = (base + p3) * (1.0 / SRATE) + initrev; hi.z = fv.w; hi.w = (float)(r - floor(r));
            float4* pp = (float4*)(prep + (size_t)b * NT + ct0);
            pp[0] = lo;
            pp[1] = hi;
        }
        carry += tot;
        fv = nxt;
    }
    if (tid == 0) {
        double rev = carry * (1.0 / SRATE) + initrev;
        double fr = rev - floor(rev);
        outf[b] = (float)(fr * TWO_PI);
    }
}

// ---------------- kernel 2: main synthesis ----------------
// 256 threads = 4 waves, 4 lanes per timestep. Preamble is pure loads:
// one float2 prep load + 4 predicated float4 amp loads. No shuffles/LDS
// before compute. Inner loop packed fp32.
__global__ __launch_bounds__(256) void k_main(const float2* __restrict__ prep,
                                              const float* __restrict__ amps,
                                              const float* __restrict__ ffq,
                                              const float* __restrict__ fbw,
                                              const float* __restrict__ fam,
                                              float* __restrict__ out) {
    int b = blockIdx.y, ch = blockIdx.x;
    int tid = threadIdx.x;
    int wv = tid >> 6, lane = tid & 63;
    int g = wv * 16 + (lane >> 2);     // timestep within chunk (0..63)
    int j = lane & 3;                  // float4 slot within row
    int t = ch * CTS + g;

    const float4* row = (const float4*)(amps + ((size_t)b * NT + (size_t)t) * NH);
    float4 q0 = row[j];                              // independent, issue at entry
    float4 q1 = row[4 + j];
    float2 pr = prep[(size_t)b * NT + t];            // f0 + phase, one 8B load
    float f0v   = pr.x;
    float f0s   = f0v * (1.0f / 256.0f);             // exact scale by 2^-8
    float rev_g = pr.y;
    float4 q2 = make_float4(0.f, 0.f, 0.f, 0.f);
    float4 q3 = make_float4(0.f, 0.f, 0.f, 0.f);
    if (f0s * 33.0f < 46.875f) q2 = row[8 + j];            // any of h 33..48 below nyq
    if (j < 3 && f0s * 49.0f < 46.875f) q3 = row[12 + j];  // h 49..60 (j==3 OOB)

    // --- formant lerp for timestep t (quad-uniform, L1-resident tables) ---
    double srcd = (double)t * (99.0 / 47999.0);
    int i0 = (int)srcd;
    if (i0 > NC - 2) i0 = NC - 2;
    float frac = (float)(srcd - (double)i0);
    float omf = 1.0f - frac;
    const float* Fq = ffq + (b * NC + i0) * NFMT;
    const float* Bw = fbw + (b * NC + i0) * NFMT;
    const float* Am = fam + (b * NC + i0) * NFMT;
    float fq_g[NFMT], c1_g[NFMT], c2_g[NFMT];
    #pragma unroll
    for (int f = 0; f < NFMT; ++f) {
        float fq = Fq[f] * omf + Fq[NFMT + f] * frac;
        float bw = Bw[f] * omf + Bw[NFMT + f] * frac;
        float am = Am[f] * omf + Am[NFMT + f] * frac;
        float bws = bw * (1.0f / 256.0f);
        fq_g[f] = fq * (1.0f / 256.0f);
        c2_g[f] = bws * bws;
        c1_g[f] = am * c2_g[f];
    }

    // --- packed-fp32 harmonic accumulation: 8 pairs per lane ---
    float4 q[4] = {q0, q1, q2, q3};
    v2f acc2 = {0.0f, 0.0f};
    float j4 = (float)(j * 4);
    #pragma unroll
    for (int i = 0; i < 4; ++i) {
        float aq[4] = {q[i].x, q[i].y, q[i].z, q[i].w};
        #pragma unroll
        for (int p = 0; p < 2; ++p) {
            float h0 = (float)(i * 16 + p * 2 + 1) + j4;
            v2f hfl = {h0, h0 + 1.0f};
            v2f aa  = {aq[p * 2], aq[p * 2 + 1]};
            v2f hs  = f0s * hfl;                   // f0*h * 2^-8 (pk mul)
            v2f pN  = {1.0f, 1.0f};
            v2f pD  = {1.0f, 1.0f};
            #pragma unroll
            for (int f = 0; f < NFMT; ++f) {
                v2f d = hs - fq_g[f];
                v2f e = d * d + c2_g[f];           // pk fma
                pN *= (e + c1_g[f]);
                pD *= e;
            }
            v2f rp;
            rp.x = __builtin_amdgcn_rcpf(pD.x);
            rp.y = __builtin_amdgcn_rcpf(pD.y);
            v2f fac = pN * rp;
            v2f ar = rev_g * hfl;
            v2f sn;
            sn.x = __builtin_amdgcn_sinf(__builtin_amdgcn_fractf(ar.x));
            sn.y = __builtin_amdgcn_sinf(__builtin_amdgcn_fractf(ar.y));
            v2f fm;
            fm.x = (hs.x < 46.875f) ? fac.x : 0.0f;   // nyquist mask (12000*2^-8)
            fm.y = (hs.y < 46.875f) ? fac.y : 0.0f;
            acc2 += (sn * aa) * fm;
        }
    }
    float acc = acc2.x + acc2.y;
    acc += __shfl_xor(acc, 1, 64);
    acc += __shfl_xor(acc, 2, 64);
    if (j == 0) {
        if (!(f0v > 0.0f)) acc = 0.0f;               // voiced mask
        out[b * NT + t] = acc;
    }
}

extern "C" void kernel_launch(void* const* d_in, const int* in_sizes, int n_in,
                              void* d_out, int out_size, void* d_ws, size_t ws_size,
                              hipStream_t stream) {
    const float* f0    = (const float*)d_in[0];
    const float* amps  = (const float*)d_in[1];
    const float* ffq   = (const float*)d_in[2];
    const float* fbw   = (const float*)d_in[3];
    const float* fam   = (const float*)d_in[4];
    const float* initp = (const float*)d_in[5];
    float* out = (float*)d_out;

    float2* prep = (float2*)d_ws;           // NB*NT float2 = 3 MB

    k_prep<<<NB, TPB, 0, stream>>>(f0, initp, prep, out + NB * NT);
    dim3 gmain(NCH, NB);
    k_main<<<gmain, 256, 0, stream>>>(prep, amps, ffq, fbw, fam, out);
}

// Round 7
// 41.185 us; speedup vs baseline: 1.2310x; 1.2310x over previous
//
#include <hip/hip_runtime.h>
#include <math.h>

#define SRATE   24000.0
#define NB      8
#define NT      48000
#define NH      60
#define NC      100
#define NFMT    5
#define CTS     64                        // timesteps per chunk
#define NCH     (NT / CTS)                // 750 chunks per batch
#define TWO_PI  6.283185307179586476925286766559

typedef float v2f __attribute__((ext_vector_type(2)));

// ---------------- kernel 1: per-chunk f0 sums (double) ----------------
__global__ __launch_bounds__(256) void k_partial(const float* __restrict__ f0,
                                                 double* __restrict__ part) {
    int b = blockIdx.y;
    int ch = blockIdx.x * 4 + (threadIdx.x >> 6);
    int lane = threadIdx.x & 63;
    if (ch < NCH) {
        int t = ch * CTS + lane;
        double q = (double)f0[b * NT + t];
        #pragma unroll
        for (int off = 32; off > 0; off >>= 1)
            q += __shfl_down(q, off, 64);
        if (lane == 0) part[b * NCH + ch] = q;
    }
}

// ------- kernel 2: per-batch block scan of 750 chunk sums + final phase -------
__global__ __launch_bounds__(256) void k_scan(const double* __restrict__ part,
                                              double* __restrict__ offs,
                                              const float* __restrict__ initp,
                                              float* __restrict__ outf) {
    int b = blockIdx.x;
    int tid = threadIdx.x;
    int lane = tid & 63, wv = tid >> 6;
    int base = tid * 3;
    double v0 = (base     < NCH) ? part[b * NCH + base    ] : 0.0;
    double v1 = (base + 1 < NCH) ? part[b * NCH + base + 1] : 0.0;
    double v2 = (base + 2 < NCH) ? part[b * NCH + base + 2] : 0.0;
    double s = v0 + v1 + v2;
    double inc = s;
    #pragma unroll
    for (int off = 1; off < 64; off <<= 1) {
        double n = __shfl_up(inc, off, 64);
        if (lane >= off) inc += n;
    }
    __shared__ double wtot[4];
    if (lane == 63) wtot[wv] = inc;
    __syncthreads();
    double woff = 0.0;
    #pragma unroll
    for (int w = 0; w < 4; ++w)
        if (w < wv) woff += wtot[w];
    double excl = woff + inc - s;              // exclusive prefix for this thread
    if (base     < NCH) offs[b * NCH + base    ] = excl;
    if (base + 1 < NCH) offs[b * NCH + base + 1] = excl + v0;
    if (base + 2 < NCH) offs[b * NCH + base + 2] = excl + v0 + v1;
    if (tid == 255) {
        double carry = woff + inc;             // grand total
        double rev = carry * (1.0 / SRATE) + (double)initp[b] * (1.0 / TWO_PI);
        double fr = rev - floor(rev);
        outf[b] = (float)(fr * TWO_PI);
    }
}

// ---- kernel 3: per-timestep phase -> prep[t] = (f0[t], rev[t]) ----
// One wave per 64-timestep chunk; f64 scan done ONCE per timestep here
// instead of redundantly in every k_main wave.
__global__ __launch_bounds__(256) void k_rev(const float* __restrict__ f0,
                                             const double* __restrict__ offs,
                                             const float* __restrict__ initp,
                                             float2* __restrict__ prep) {
    int b = blockIdx.y;
    int ch = blockIdx.x * 4 + (threadIdx.x >> 6);
    int lane = threadIdx.x & 63;
    if (ch >= NCH) return;
    int t = ch * CTS + lane;
    float f0v = f0[b * NT + t];
    double inc = (double)f0v;
    #pragma unroll
    for (int off = 1; off < 64; off <<= 1) {
        double n = __shfl_up(inc, off, 64);
        if (lane >= off) inc += n;
    }
    double rev = (offs[b * NCH + ch] + inc) * (1.0 / SRATE)
               + (double)initp[b] * (1.0 / TWO_PI);
    float rev_f = (float)(rev - floor(rev));
    prep[(size_t)b * NT + t] = make_float2(f0v, rev_f);
}

// ---------------- kernel 4: main synthesis ----------------
// 256 threads = 4 waves, 4 lanes per timestep. Preamble = 6 independent
// loads issued at entry (4 amp float4 + 1 prep float2 + formant tables).
// No shuffles, no f64, no LDS before compute. Inner loop packed fp32.
__global__ __launch_bounds__(256, 4) void k_main(const float2* __restrict__ prep,
                                                 const float* __restrict__ amps,
                                                 const float* __restrict__ ffq,
                                                 const float* __restrict__ fbw,
                                                 const float* __restrict__ fam,
                                                 float* __restrict__ out) {
    int b = blockIdx.y, ch = blockIdx.x;
    int tid = threadIdx.x;
    int wv = tid >> 6, lane = tid & 63;
    int g = wv * 16 + (lane >> 2);     // timestep within chunk (0..63)
    int j = lane & 3;                  // float4 slot within row
    int t = ch * CTS + g;

    // --- all loads unconditional & independent: max MLP at entry ---
    const float4* row = (const float4*)(amps + ((size_t)b * NT + (size_t)t) * NH);
    float4 q0 = row[j];
    float4 q1 = row[4 + j];
    float4 q2 = row[8 + j];
    float4 q3 = (j < 3) ? row[12 + j] : make_float4(0.f, 0.f, 0.f, 0.f);
    float2 pr = prep[(size_t)b * NT + t];
    float f0v   = pr.x;
    float f0s   = f0v * (1.0f / 256.0f);             // exact scale by 2^-8
    float rev_g = pr.y;

    // --- formant lerp for timestep t (quad-uniform, L2-resident tables) ---
    double srcd = (double)t * (99.0 / 47999.0);
    int i0 = (int)srcd;
    if (i0 > NC - 2) i0 = NC - 2;
    float frac = (float)(srcd - (double)i0);
    float omf = 1.0f - frac;
    const float* Fq = ffq + (b * NC + i0) * NFMT;
    const float* Bw = fbw + (b * NC + i0) * NFMT;
    const float* Am = fam + (b * NC + i0) * NFMT;
    float fq_g[NFMT], c1_g[NFMT], c2_g[NFMT];
    #pragma unroll
    for (int f = 0; f < NFMT; ++f) {
        float fq = Fq[f] * omf + Fq[NFMT + f] * frac;
        float bw = Bw[f] * omf + Bw[NFMT + f] * frac;
        float am = Am[f] * omf + Am[NFMT + f] * frac;
        float bws = bw * (1.0f / 256.0f);
        fq_g[f] = fq * (1.0f / 256.0f);
        c2_g[f] = bws * bws;
        c1_g[f] = am * c2_g[f];
    }

    // --- packed-fp32 harmonic accumulation: 8 pairs per lane ---
    float4 q[4] = {q0, q1, q2, q3};
    v2f acc2 = {0.0f, 0.0f};
    float j4 = (float)(j * 4);
    #pragma unroll
    for (int i = 0; i < 4; ++i) {
        float aq[4] = {q[i].x, q[i].y, q[i].z, q[i].w};
        #pragma unroll
        for (int p = 0; p < 2; ++p) {
            float h0 = (float)(i * 16 + p * 2 + 1) + j4;
            v2f hfl = {h0, h0 + 1.0f};
            v2f aa  = {aq[p * 2], aq[p * 2 + 1]};
            v2f hs  = f0s * hfl;                   // f0*h * 2^-8
            v2f pN  = {1.0f, 1.0f};
            v2f pD  = {1.0f, 1.0f};
            #pragma unroll
            for (int f = 0; f < NFMT; ++f) {
                v2f d = hs - fq_g[f];
                v2f e = d * d + c2_g[f];
                pN *= (e + c1_g[f]);
                pD *= e;
            }
            v2f rp;
            rp.x = __builtin_amdgcn_rcpf(pD.x);
            rp.y = __builtin_amdgcn_rcpf(pD.y);
            v2f fac = pN * rp;
            v2f ar = rev_g * hfl;
            v2f sn;
            sn.x = __builtin_amdgcn_sinf(__builtin_amdgcn_fractf(ar.x));
            sn.y = __builtin_amdgcn_sinf(__builtin_amdgcn_fractf(ar.y));
            v2f fm;
            fm.x = (hs.x < 46.875f) ? fac.x : 0.0f;   // nyquist mask (12000*2^-8)
            fm.y = (hs.y < 46.875f) ? fac.y : 0.0f;
            acc2 += (sn * aa) * fm;
        }
    }
    float acc = acc2.x + acc2.y;
    acc += __shfl_xor(acc, 1, 64);
    acc += __shfl_xor(acc, 2, 64);
    if (j == 0) {
        if (!(f0v > 0.0f)) acc = 0.0f;               // voiced mask
        out[b * NT + t] = acc;
    }
}

extern "C" void kernel_launch(void* const* d_in, const int* in_sizes, int n_in,
                              void* d_out, int out_size, void* d_ws, size_t ws_size,
                              hipStream_t stream) {
    const float* f0    = (const float*)d_in[0];
    const float* amps  = (const float*)d_in[1];
    const float* ffq   = (const float*)d_in[2];
    const float* fbw   = (const float*)d_in[3];
    const float* fam   = (const float*)d_in[4];
    const float* initp = (const float*)d_in[5];
    float* out = (float*)d_out;

    double* part = (double*)d_ws;                    // NB*NCH doubles
    double* offs = part + NB * NCH;                  // NB*NCH doubles
    float2* prep = (float2*)(offs + NB * NCH);       // NB*NT float2 = 3 MB

    dim3 gchunk((NCH + 3) / 4, NB);
    k_partial<<<gchunk, 256, 0, stream>>>(f0, part);
    k_scan<<<NB, 256, 0, stream>>>(part, offs, initp, out + NB * NT);
    k_rev<<<gchunk, 256, 0, stream>>>(f0, offs, initp, prep);
    dim3 gmain(NCH, NB);
    k_main<<<gmain, 256, 0, stream>>>(prep, amps, ffq, fbw, fam, out);
}

// Round 8
// 35.438 us; speedup vs baseline: 1.4306x; 1.1621x over previous
//
#include <hip/hip_runtime.h>
#include <math.h>

#define SRATE   24000.0
#define NB      8
#define NT      48000
#define NH      60
#define NC      100
#define NFMT    5
#define CTS     64                        // timesteps per chunk (= per wave)
#define NCH     (NT / CTS)                // 750 chunks per batch
#define TWO_PI  6.283185307179586476925286766559

typedef float v2f __attribute__((ext_vector_type(2)));

// ---------------- kernel 1: per-chunk f0 sums (double) ----------------
__global__ __launch_bounds__(256) void k_partial(const float* __restrict__ f0,
                                                 double* __restrict__ part) {
    int b = blockIdx.y;
    int ch = blockIdx.x * 4 + (threadIdx.x >> 6);
    int lane = threadIdx.x & 63;
    if (ch < NCH) {
        int t = ch * CTS + lane;
        double q = (double)f0[b * NT + t];
        #pragma unroll
        for (int off = 32; off > 0; off >>= 1)
            q += __shfl_down(q, off, 64);
        if (lane == 0) part[b * NCH + ch] = q;
    }
}

// ------- kernel 2: per-batch block scan of 750 chunk sums + final phase -------
__global__ __launch_bounds__(256) void k_scan(const double* __restrict__ part,
                                              double* __restrict__ offs,
                                              const float* __restrict__ initp,
                                              float* __restrict__ outf) {
    int b = blockIdx.x;
    int tid = threadIdx.x;
    int lane = tid & 63, wv = tid >> 6;
    int base = tid * 3;
    double v0 = (base     < NCH) ? part[b * NCH + base    ] : 0.0;
    double v1 = (base + 1 < NCH) ? part[b * NCH + base + 1] : 0.0;
    double v2 = (base + 2 < NCH) ? part[b * NCH + base + 2] : 0.0;
    double s = v0 + v1 + v2;
    double inc = s;
    #pragma unroll
    for (int off = 1; off < 64; off <<= 1) {
        double n = __shfl_up(inc, off, 64);
        if (lane >= off) inc += n;
    }
    __shared__ double wtot[4];
    if (lane == 63) wtot[wv] = inc;
    __syncthreads();
    double woff = 0.0;
    #pragma unroll
    for (int w = 0; w < 4; ++w)
        if (w < wv) woff += wtot[w];
    double excl = woff + inc - s;              // exclusive prefix for this thread
    if (base     < NCH) offs[b * NCH + base    ] = excl;
    if (base + 1 < NCH) offs[b * NCH + base + 1] = excl + v0;
    if (base + 2 < NCH) offs[b * NCH + base + 2] = excl + v0 + v1;
    if (tid == 255) {
        double carry = woff + inc;             // grand total
        double rev = carry * (1.0 / SRATE) + (double)initp[b] * (1.0 / TWO_PI);
        double fr = rev - floor(rev);
        outf[b] = (float)(fr * TWO_PI);
    }
}

// ---------------- kernel 3: main synthesis ----------------
// 256 threads = 4 waves; each wave owns one full 64-ts chunk, processed as
// 4 passes of 16 timesteps (4 lanes each). Amp loads are register
// double-buffered across passes; the per-chunk f64 phase scan runs once per
// wave, overlapped with pass-0 load latency. No LDS, no barriers.
__global__ __launch_bounds__(256) void k_main(const float* __restrict__ f0,
                                              const float* __restrict__ amps,
                                              const float* __restrict__ ffq,
                                              const float* __restrict__ fbw,
                                              const float* __restrict__ fam,
                                              const float* __restrict__ initp,
                                              const double* __restrict__ offs,
                                              float* __restrict__ out) {
    int b = blockIdx.y;
    int ch = blockIdx.x * 4 + (threadIdx.x >> 6);
    int lane = threadIdx.x & 63;
    if (ch >= NCH) return;
    int t0 = ch * CTS;
    int g0 = lane >> 2, j = lane & 3;

    const float* rowbase = amps + ((size_t)b * NT + t0) * NH;

    // ---- pass-0 amplitude loads: issue at cycle 0 ----
    const float4* r0 = (const float4*)(rowbase + (size_t)g0 * NH);
    float4 A0 = r0[j], A1 = r0[4 + j], A2 = r0[8 + j];
    float4 A3 = (j < 3) ? r0[12 + j] : make_float4(0.f, 0.f, 0.f, 0.f);

    // ---- per-lane (lane = ts) inputs: f0 + formant table values ----
    int tl = t0 + lane;
    float f0v = f0[b * NT + tl];
    double srcd = (double)tl * (99.0 / 47999.0);
    int i0 = (int)srcd;
    if (i0 > NC - 2) i0 = NC - 2;
    float frac = (float)(srcd - (double)i0);
    float omf = 1.0f - frac;
    const float* Fq = ffq + (b * NC + i0) * NFMT;
    const float* Bw = fbw + (b * NC + i0) * NFMT;
    const float* Am = fam + (b * NC + i0) * NFMT;
    float fqa[NFMT], fqb[NFMT], bwa[NFMT], bwb[NFMT], ama[NFMT], amb[NFMT];
    #pragma unroll
    for (int f = 0; f < NFMT; ++f) {
        fqa[f] = Fq[f]; fqb[f] = Fq[NFMT + f];
        bwa[f] = Bw[f]; bwb[f] = Bw[NFMT + f];
        ama[f] = Am[f]; amb[f] = Am[NFMT + f];
    }

    // ---- f64 phase scan (overlaps outstanding loads) ----
    double inc = (double)f0v;
    #pragma unroll
    for (int off = 1; off < 64; off <<= 1) {
        double n = __shfl_up(inc, off, 64);
        if (lane >= off) inc += n;
    }
    double rev = (offs[b * NCH + ch] + inc) * (1.0 / SRATE)
               + (double)initp[b] * (1.0 / TWO_PI);
    float rev_l = (float)(rev - floor(rev));
    float f0s_l = f0v * (1.0f / 256.0f);           // exact 2^-8 scale

    // ---- per-lane lerp coefficients (held in regs, shuffled per pass) ----
    float fqs[NFMT], c1s[NFMT], c2s[NFMT];
    #pragma unroll
    for (int f = 0; f < NFMT; ++f) {
        float fq = fqa[f] * omf + fqb[f] * frac;
        float bw = bwa[f] * omf + bwb[f] * frac;
        float am = ama[f] * omf + amb[f] * frac;
        float bws = bw * (1.0f / 256.0f);
        fqs[f] = fq * (1.0f / 256.0f);
        c2s[f] = bws * bws;
        c1s[f] = am * c2s[f];
    }

    float j4 = (float)(j * 4);

    auto do_pass = [&](int p, float4 q0, float4 q1, float4 q2, float4 q3) {
        int gp = p * 16 + g0;                      // ts within chunk
        float f0s   = __shfl(f0s_l, gp, 64);
        float rev_g = __shfl(rev_l, gp, 64);
        float fq_g[NFMT], c1_g[NFMT], c2_g[NFMT];
        #pragma unroll
        for (int f = 0; f < NFMT; ++f) {
            fq_g[f] = __shfl(fqs[f], gp, 64);
            c1_g[f] = __shfl(c1s[f], gp, 64);
            c2_g[f] = __shfl(c2s[f], gp, 64);
        }
        float4 q[4] = {q0, q1, q2, q3};            // static-indexed (unrolled)
        v2f acc2 = {0.0f, 0.0f};
        #pragma unroll
        for (int i = 0; i < 4; ++i) {
            float aq[4] = {q[i].x, q[i].y, q[i].z, q[i].w};
            #pragma unroll
            for (int pp = 0; pp < 2; ++pp) {
                float h0 = (float)(i * 16 + pp * 2 + 1) + j4;
                v2f hfl = {h0, h0 + 1.0f};
                v2f aa  = {aq[pp * 2], aq[pp * 2 + 1]};
                v2f hs  = f0s * hfl;               // f0*h * 2^-8
                v2f pN  = {1.0f, 1.0f};
                v2f pD  = {1.0f, 1.0f};
                #pragma unroll
                for (int f = 0; f < NFMT; ++f) {
                    v2f d = hs - fq_g[f];
                    v2f e = d * d + c2_g[f];
                    pN *= (e + c1_g[f]);
                    pD *= e;
                }
                v2f rp;
                rp.x = __builtin_amdgcn_rcpf(pD.x);
                rp.y = __builtin_amdgcn_rcpf(pD.y);
                v2f fac = pN * rp;
                v2f ar = rev_g * hfl;
                v2f sn;
                sn.x = __builtin_amdgcn_sinf(__builtin_amdgcn_fractf(ar.x));
                sn.y = __builtin_amdgcn_sinf(__builtin_amdgcn_fractf(ar.y));
                v2f fm;
                fm.x = (hs.x < 46.875f) ? fac.x : 0.0f;   // nyq mask (12000*2^-8)
                fm.y = (hs.y < 46.875f) ? fac.y : 0.0f;
                acc2 += (sn * aa) * fm;
            }
        }
        float acc = acc2.x + acc2.y;
        acc += __shfl_xor(acc, 1, 64);
        acc += __shfl_xor(acc, 2, 64);
        if (j == 0) {
            if (!(f0s > 0.0f)) acc = 0.0f;         // voiced mask
            out[b * NT + t0 + gp] = acc;
        }
    };

    // ---- software-pipelined passes: loads for p+1 issue before compute p ----
    const float4* r1 = (const float4*)(rowbase + (size_t)(16 + g0) * NH);
    float4 B0 = r1[j], B1 = r1[4 + j], B2 = r1[8 + j];
    float4 B3 = (j < 3) ? r1[12 + j] : make_float4(0.f, 0.f, 0.f, 0.f);
    do_pass(0, A0, A1, A2, A3);

    const float4* r2 = (const float4*)(rowbase + (size_t)(32 + g0) * NH);
    A0 = r2[j]; A1 = r2[4 + j]; A2 = r2[8 + j];
    A3 = (j < 3) ? r2[12 + j] : make_float4(0.f, 0.f, 0.f, 0.f);
    do_pass(1, B0, B1, B2, B3);

    const float4* r3 = (const float4*)(rowbase + (size_t)(48 + g0) * NH);
    B0 = r3[j]; B1 = r3[4 + j]; B2 = r3[8 + j];
    B3 = (j < 3) ? r3[12 + j] : make_float4(0.f, 0.f, 0.f, 0.f);
    do_pass(2, A0, A1, A2, A3);

    do_pass(3, B0, B1, B2, B3);
}

extern "C" void kernel_launch(void* const* d_in, const int* in_sizes, int n_in,
                              void* d_out, int out_size, void* d_ws, size_t ws_size,
                              hipStream_t stream) {
    const float* f0    = (const float*)d_in[0];
    const float* amps  = (const float*)d_in[1];
    const float* ffq   = (const float*)d_in[2];
    const float* fbw   = (const float*)d_in[3];
    const float* fam   = (const float*)d_in[4];
    const float* initp = (const float*)d_in[5];
    float* out = (float*)d_out;

    double* part = (double*)d_ws;                    // NB*NCH doubles
    double* offs = part + NB * NCH;                  // NB*NCH doubles

    dim3 gchunk((NCH + 3) / 4, NB);
    k_partial<<<gchunk, 256, 0, stream>>>(f0, part);
    k_scan<<<NB, 256, 0, stream>>>(part, offs, initp, out + NB * NT);
    k_main<<<gchunk, 256, 0, stream>>>(f0, amps, ffq, fbw, fam, initp, offs, out);
}

// Round 9
// 33.200 us; speedup vs baseline: 1.5271x; 1.0674x over previous
//
#include <hip/hip_runtime.h>
#include <math.h>

#define SRATE   24000.0
#define NB      8
#define NT      48000
#define NH      60
#define NC      100
#define NFMT    5
#define CTS     64
#define NCH     (NT / CTS)       // 750 chunks per batch
#define NPAIR   (NCH / 2)        // 375 chunk-pairs (128 ts each)
#define TWO_PI  6.283185307179586476925286766559
#define PSC     (1.0f / 1024.0f) // exact 2^-10 prescale (overflow-safe pair products)
#define NYQS    11.71875f        // 12000 * 2^-10 (exact)

typedef float v2f __attribute__((ext_vector_type(2)));

// ---------------- kernel 1: per-chunk f0 sums (double) ----------------
__global__ __launch_bounds__(256) void k_partial(const float* __restrict__ f0,
                                                 double* __restrict__ part) {
    int b = blockIdx.y;
    int ch = blockIdx.x * 4 + (threadIdx.x >> 6);
    int lane = threadIdx.x & 63;
    if (ch < NCH) {
        int t = ch * CTS + lane;
        double q = (double)f0[b * NT + t];
        #pragma unroll
        for (int off = 32; off > 0; off >>= 1)
            q += __shfl_down(q, off, 64);
        if (lane == 0) part[b * NCH + ch] = q;
    }
}

// ---------------- kernel 2: main synthesis ----------------
// 256 threads = 4 waves; each wave owns 128 timesteps (2 chunks, 8 passes of
// 16 ts x 4 lanes). Each wave computes its own chunk-prefix from part[]
// (L2-broadcast reduce, hidden under prologue amp loads). Per lane a pass
// covers 16 CONTIGUOUS harmonics; sines come from 8 direct seeds + packed
// Chebyshev recurrence. Register double-buffered amp loads across passes.
__global__ __launch_bounds__(256) void k_main(const float* __restrict__ f0,
                                              const float* __restrict__ amps,
                                              const float* __restrict__ ffq,
                                              const float* __restrict__ fbw,
                                              const float* __restrict__ fam,
                                              const float* __restrict__ initp,
                                              const double* __restrict__ part,
                                              float* __restrict__ out) {
    int b = blockIdx.y;
    int cp = blockIdx.x * 4 + (threadIdx.x >> 6);
    int lane = threadIdx.x & 63;
    if (cp >= NPAIR) return;
    int ch0 = cp * 2;
    int t0 = cp * 128;                 // first ts of this wave (within batch)
    int g0 = lane >> 2, j = lane & 3;

    const float* ab = amps + (size_t)b * NT * NH;

    // ---- prologue amp loads: passes 0 and 1, issued at cycle 0 ----
    const float4* r0 = (const float4*)(ab + (size_t)(t0 + g0) * NH);
    float4 A0 = r0[j * 4], A1 = r0[j * 4 + 1], A2 = r0[j * 4 + 2];
    float4 A3 = (j < 3) ? r0[j * 4 + 3] : make_float4(0.f, 0.f, 0.f, 0.f);
    const float4* r1 = (const float4*)(ab + (size_t)(t0 + 16 + g0) * NH);
    float4 B0 = r1[j * 4], B1 = r1[j * 4 + 1], B2 = r1[j * 4 + 2];
    float4 B3 = (j < 3) ? r1[j * 4 + 3] : make_float4(0.f, 0.f, 0.f, 0.f);

    // ---- per-wave prefix over chunk sums (masked reduce, L2-broadcast) ----
    const double* pb = part + b * NCH;
    double sl = 0.0;
    #pragma unroll
    for (int k = 0; k < 12; ++k) {
        int idx = k * 64 + lane;
        double v = (idx < NCH) ? pb[idx] : 0.0;
        if (idx < ch0) sl += v;
    }
    #pragma unroll
    for (int off = 1; off < 64; off <<= 1)
        sl += __shfl_xor(sl, off, 64);

    double initrev = (double)initp[b] * (1.0 / TWO_PI);

    // designated wave writes final phase
    if (cp == 0) {
        double sa = 0.0;
        #pragma unroll
        for (int k = 0; k < 12; ++k) {
            int idx = k * 64 + lane;
            if (idx < NCH) sa += pb[idx];
        }
        #pragma unroll
        for (int off = 1; off < 64; off <<= 1)
            sa += __shfl_xor(sa, off, 64);
        if (lane == 0) {
            double rv = sa * (1.0 / SRATE) + initrev;
            out[NB * NT + b] = (float)((rv - floor(rv)) * TWO_PI);
        }
    }

    // ---- per-chunk preamble: f64 scan + formant lerp (lane = ts) ----
    float revA, f0sA, revB, f0sB;
    float fqA[NFMT], c1A[NFMT], c2A[NFMT], fqB[NFMT], c1B[NFMT], c2B[NFMT];

    auto chunk_pre = [&](int tl, double prefd, float& rev_o, float& f0s_o,
                         float (&fqo)[NFMT], float (&c1o)[NFMT],
                         float (&c2o)[NFMT]) -> double {
        float f0v = f0[b * NT + tl];
        double inc = (double)f0v;
        #pragma unroll
        for (int off = 1; off < 64; off <<= 1) {
            double n = __shfl_up(inc, off, 64);
            if (lane >= off) inc += n;
        }
        double rev = (prefd + inc) * (1.0 / SRATE) + initrev;
        rev_o = (float)(rev - floor(rev));
        f0s_o = f0v * PSC;
        double srcd = (double)tl * (99.0 / 47999.0);
        int i0 = (int)srcd;
        if (i0 > NC - 2) i0 = NC - 2;
        float frac = (float)(srcd - (double)i0);
        float omf = 1.0f - frac;
        const float* Fq = ffq + (b * NC + i0) * NFMT;
        const float* Bw = fbw + (b * NC + i0) * NFMT;
        const float* Am = fam + (b * NC + i0) * NFMT;
        #pragma unroll
        for (int f = 0; f < NFMT; ++f) {
            float fqv = Fq[f] * omf + Fq[NFMT + f] * frac;
            float bwv = Bw[f] * omf + Bw[NFMT + f] * frac;
            float amv = Am[f] * omf + Am[NFMT + f] * frac;
            float bws = bwv * PSC;
            fqo[f] = fqv * PSC;
            c2o[f] = bws * bws;
            c1o[f] = amv * c2o[f];
        }
        return __shfl(inc, 63, 64);        // chunk total (all lanes)
    };

    double tot0 = chunk_pre(t0 + lane, sl, revA, f0sA, fqA, c1A, c2A);
    chunk_pre(t0 + 64 + lane, sl + tot0, revB, f0sB, fqB, c1B, c2B);

    // ---- one pass = 16 ts x 4 lanes, 16 contiguous harmonics per lane ----
    auto do_pass = [&](int p, float revLane, float f0sLane,
                       const float (&fqL)[NFMT], const float (&c1L)[NFMT],
                       const float (&c2L)[NFMT],
                       float4 q0, float4 q1, float4 q2, float4 q3) {
        int gp = ((p & 3) << 4) + g0;
        float f0s   = __shfl(f0sLane, gp, 64);
        float rev_g = __shfl(revLane, gp, 64);
        float fq[NFMT], c1[NFMT], c2[NFMT];
        #pragma unroll
        for (int f = 0; f < NFMT; ++f) {
            fq[f] = __shfl(fqL[f], gp, 64);
            c1[f] = __shfl(c1L[f], gp, 64);
            c2[f] = __shfl(c2L[f], gp, 64);
        }
        float hb = (float)(j << 4);
        auto sd = [&](float k) {
            return __builtin_amdgcn_sinf(
                __builtin_amdgcn_fractf((hb + k) * rev_g));
        };
        float cc = __builtin_amdgcn_cosf(
            __builtin_amdgcn_fractf(2.0f * rev_g));     // cos(2*theta)
        v2f cv = {2.0f * cc, 2.0f * cc};
        v2f pr0 = {sd(1.0f), sd(2.0f)};
        v2f pr1 = {sd(3.0f), sd(4.0f)};
        v2f pr2 = cv * pr1 - pr0;                       // (s5,s6)
        v2f pr3 = cv * pr2 - pr1;                       // (s7,s8)
        v2f pr4 = {sd(9.0f), sd(10.0f)};
        v2f pr5 = {sd(11.0f), sd(12.0f)};
        v2f pr6 = cv * pr5 - pr4;                       // (s13,s14)
        v2f pr7 = cv * pr6 - pr5;                       // (s15,s16)
        v2f acc2 = {0.0f, 0.0f};
        auto pairf = [&](float h1, v2f sn, float a0, float a1) {
            v2f hfl = {h1, h1 + 1.0f};
            v2f hs = f0s * hfl;                         // f0*h * 2^-10
            v2f pN = {1.0f, 1.0f}, pD = {1.0f, 1.0f};
            #pragma unroll
            for (int f = 0; f < NFMT; ++f) {
                v2f d = hs - fq[f];
                v2f e = d * d + c2[f];
                pN *= e + c1[f];
                pD *= e;
            }
            float R = __builtin_amdgcn_rcpf(pD.x * pD.y);
            v2f fac = {pN.x * pD.y * R, pN.y * pD.x * R};
            v2f fm;
            fm.x = (hs.x < NYQS) ? fac.x : 0.0f;        // nyquist mask
            fm.y = (hs.y < NYQS) ? fac.y : 0.0f;
            v2f aa = {a0, a1};
            acc2 += (sn * aa) * fm;
        };
        pairf(hb + 1.0f,  pr0, q0.x, q0.y);
        pairf(hb + 3.0f,  pr1, q0.z, q0.w);
        pairf(hb + 5.0f,  pr2, q1.x, q1.y);
        pairf(hb + 7.0f,  pr3, q1.z, q1.w);
        pairf(hb + 9.0f,  pr4, q2.x, q2.y);
        pairf(hb + 11.0f, pr5, q2.z, q2.w);
        pairf(hb + 13.0f, pr6, q3.x, q3.y);
        pairf(hb + 15.0f, pr7, q3.z, q3.w);
        float acc = acc2.x + acc2.y;
        acc += __shfl_xor(acc, 1, 64);
        acc += __shfl_xor(acc, 2, 64);
        if (j == 0) {
            if (!(f0s > 0.0f)) acc = 0.0f;              // voiced mask
            out[b * NT + t0 + (p << 4) + g0] = acc;
        }
    };

    // ---- 8 passes, register double-buffered, runtime loop (I-cache) ----
    #pragma unroll 1
    for (int pg = 0; pg < 8; pg += 2) {
        bool cB = pg >= 4;
        float revL = cB ? revB : revA;
        float f0sL = cB ? f0sB : f0sA;
        float fqL[NFMT], c1L[NFMT], c2L[NFMT];
        #pragma unroll
        for (int f = 0; f < NFMT; ++f) {
            fqL[f] = cB ? fqB[f] : fqA[f];
            c1L[f] = cB ? c1B[f] : c1A[f];
            c2L[f] = cB ? c2B[f] : c2A[f];
        }
        do_pass(pg, revL, f0sL, fqL, c1L, c2L, A0, A1, A2, A3);
        if (pg < 6) {
            const float4* rr =
                (const float4*)(ab + (size_t)(t0 + (pg + 2) * 16 + g0) * NH);
            A0 = rr[j * 4]; A1 = rr[j * 4 + 1]; A2 = rr[j * 4 + 2];
            A3 = (j < 3) ? rr[j * 4 + 3] : make_float4(0.f, 0.f, 0.f, 0.f);
        }
        do_pass(pg + 1, revL, f0sL, fqL, c1L, c2L, B0, B1, B2, B3);
        if (pg < 6) {
            const float4* rr =
                (const float4*)(ab + (size_t)(t0 + (pg + 3) * 16 + g0) * NH);
            B0 = rr[j * 4]; B1 = rr[j * 4 + 1]; B2 = rr[j * 4 + 2];
            B3 = (j < 3) ? rr[j * 4 + 3] : make_float4(0.f, 0.f, 0.f, 0.f);
        }
    }
}

extern "C" void kernel_launch(void* const* d_in, const int* in_sizes, int n_in,
                              void* d_out, int out_size, void* d_ws, size_t ws_size,
                              hipStream_t stream) {
    const float* f0    = (const float*)d_in[0];
    const float* amps  = (const float*)d_in[1];
    const float* ffq   = (const float*)d_in[2];
    const float* fbw   = (const float*)d_in[3];
    const float* fam   = (const float*)d_in[4];
    const float* initp = (const float*)d_in[5];
    float* out = (float*)d_out;

    double* part = (double*)d_ws;                    // NB*NCH doubles (48 KB)

    dim3 gpart((NCH + 3) / 4, NB);
    k_partial<<<gpart, 256, 0, stream>>>(f0, part);
    dim3 gmain((NPAIR + 3) / 4, NB);
    k_main<<<gmain, 256, 0, stream>>>(f0, amps, ffq, fbw, fam, initp, part, out);
}